// Round 5
// baseline (3845.519 us; speedup 1.0000x reference)
//
#include <hip/hip_runtime.h>

// ============================================================================
// 2-layer tanh RNN (B=128,S=512,IN=128,H=512) + linear head (C=1000) + logsoftmax
//
// Round-5: batch-partitioned recurrence, register plan that FITS.
//   R4 failure: __launch_bounds__(512,2) caps 256 regs/wave; 192 pinned W regs
//   + working set spilled to scratch (VGPR_Count=128 proved it) -> every step
//   re-read W from scratch/L2. Fix: 256 thr/WG, 1 wave/SIMD, 512-reg budget.
//   - 8 WGs; WG owns 16 batches, full H=512. Wave owns 8 j-tiles (128 j).
//   - W_hh: kt 0..11 in VGPRs (384/thread, pinned; 478 total < 512 spill pt),
//     kt 12..15 in LDS (128 KB, loaded once). Zero per-step W from L2.
//   - h: LDS [2][16][512] bf16 double buffer, min-phase swizzle.
//   - LDS = 32768 + 131072 = 163840 B (exactly 160 KiB, launches — R4 proved).
//   - 4 waves (not 8) also HALVES h-duplication: LDS 192 KB/step vs 256.
//
// ws layout: bufA = ws (64 MB): xp0/hs0 in place; Wpk1 at head later;
//            hlast @ ws+1MB; bufB = ws+64MB: Wpk0 at head, later xp1.
// ============================================================================

using short8  = __attribute__((ext_vector_type(8))) short;
using floatx4 = __attribute__((ext_vector_type(4))) float;

#define DEV static __device__ __forceinline__
#define PIN(x) asm volatile("" : "+v"(x))

DEV unsigned short f2bf(float f) {
    union { float f; unsigned u; } v; v.f = f;
    unsigned r = (v.u + 0x7fffu + ((v.u >> 16) & 1u)) >> 16;
    return (unsigned short)r;
}
DEV float bf2f(unsigned short h) {
    union { unsigned u; float f; } v; v.u = ((unsigned)h) << 16;
    return v.f;
}
DEV float tanh_fast(float x) {
    // tanh(x) = 1 - 2/(e^{2x}+1); saturates correctly at +/-inf
    float e = __expf(2.0f * x);
    return 1.0f - 2.0f * __builtin_amdgcn_rcpf(e + 1.0f);
}

// ---------------------------------------------------------------------------
// prepack: W_hh fp32 [512][512] -> bf16 A-frag order.
// frag = jtg*16 + kt; lane holds j = jtg*16+(lane&15), k = kt*32+(lane>>4)*8+e.
// ---------------------------------------------------------------------------
__global__ void prepack_kernel(const float* __restrict__ W,
                               unsigned short* __restrict__ Wpk)
{
    const int gid  = blockIdx.x * 256 + threadIdx.x;   // 0..32767
    const int lane = gid & 63;
    const int frag = gid >> 6;                         // 0..511
    const int kt   = frag & 15;
    const int jtg  = frag >> 4;
    const int j    = jtg * 16 + (lane & 15);
    const int k    = kt * 32 + (lane >> 4) * 8;
    const float* src = W + (size_t)j * 512 + k;
    float4 a = *(const float4*)(src);
    float4 b = *(const float4*)(src + 4);
    short8 p;
    p[0]=(short)f2bf(a.x); p[1]=(short)f2bf(a.y);
    p[2]=(short)f2bf(a.z); p[3]=(short)f2bf(a.w);
    p[4]=(short)f2bf(b.x); p[5]=(short)f2bf(b.y);
    p[6]=(short)f2bf(b.z); p[7]=(short)f2bf(b.w);
    *(short8*)(Wpk + (size_t)gid * 8) = p;
}

// ---------------------------------------------------------------------------
// proj: out[m=t*128+b][n] = bf16( A[m][:]·W[n][:] + b1[n]+b2[n] )  (unchanged)
// ---------------------------------------------------------------------------
template <int K, int MODE>
__global__ __launch_bounds__(256, 2) void proj_kernel(
    const void* __restrict__ Aptr, const float* __restrict__ W,
    const float* __restrict__ b1, const float* __restrict__ b2,
    unsigned short* __restrict__ out)
{
    constexpr int LDA = 40;
    __shared__ unsigned short As[128 * LDA];
    __shared__ unsigned short Ws[64 * LDA];

    const int tid  = threadIdx.x;
    const int lane = tid & 63, wave = tid >> 6;
    const int lm   = lane & 15, lq = lane >> 4;
    const int nbase = blockIdx.x * 64;
    const int mtile = blockIdx.y;
    const int mbase = mtile * 128;

    floatx4 acc[2][4] = {};

    const int ar = tid >> 1, ak = (tid & 1) * 16;
    const int wr = tid >> 2, wk = (tid & 3) * 8;

    for (int k0 = 0; k0 < K; k0 += 32) {
        if (MODE == 0) {
            const float* x   = (const float*)Aptr;
            const float* src = x + ((size_t)ar * 512 + mtile) * 128 + (k0 + ak);
            float4 f0 = *(const float4*)(src + 0);
            float4 f1 = *(const float4*)(src + 4);
            float4 f2 = *(const float4*)(src + 8);
            float4 f3 = *(const float4*)(src + 12);
            unsigned short* d = As + ar * LDA + ak;
            d[0]=f2bf(f0.x); d[1]=f2bf(f0.y); d[2]=f2bf(f0.z); d[3]=f2bf(f0.w);
            d[4]=f2bf(f1.x); d[5]=f2bf(f1.y); d[6]=f2bf(f1.z); d[7]=f2bf(f1.w);
            d[8]=f2bf(f2.x); d[9]=f2bf(f2.y); d[10]=f2bf(f2.z); d[11]=f2bf(f2.w);
            d[12]=f2bf(f3.x); d[13]=f2bf(f3.y); d[14]=f2bf(f3.z); d[15]=f2bf(f3.w);
        } else {
            const unsigned short* h =
                (const unsigned short*)Aptr + (size_t)(mbase + ar) * K + k0 + ak;
            short8 v0 = *(const short8*)(h);
            short8 v1 = *(const short8*)(h + 8);
            *(short8*)(As + ar * LDA + ak)     = v0;
            *(short8*)(As + ar * LDA + ak + 8) = v1;
        }
        {
            const float* src = W + (size_t)(nbase + wr) * K + k0 + wk;
            float4 f0 = *(const float4*)(src);
            float4 f1 = *(const float4*)(src + 4);
            unsigned short* d = Ws + wr * LDA + wk;
            d[0]=f2bf(f0.x); d[1]=f2bf(f0.y); d[2]=f2bf(f0.z); d[3]=f2bf(f0.w);
            d[4]=f2bf(f1.x); d[5]=f2bf(f1.y); d[6]=f2bf(f1.z); d[7]=f2bf(f1.w);
        }
        __syncthreads();

        short8 af0 = *(const short8*)(As + (wave * 32 +  0 + lm) * LDA + lq * 8);
        short8 af1 = *(const short8*)(As + (wave * 32 + 16 + lm) * LDA + lq * 8);
        #pragma unroll
        for (int nt = 0; nt < 4; ++nt) {
            short8 bf = *(const short8*)(Ws + (nt * 16 + lm) * LDA + lq * 8);
            acc[0][nt] = __builtin_amdgcn_mfma_f32_16x16x32_bf16(af0, bf, acc[0][nt], 0, 0, 0);
            acc[1][nt] = __builtin_amdgcn_mfma_f32_16x16x32_bf16(af1, bf, acc[1][nt], 0, 0, 0);
        }
        __syncthreads();
    }

    #pragma unroll
    for (int nt = 0; nt < 4; ++nt) {
        const int n = nbase + nt * 16 + lm;
        const float bias = b1[n] + b2[n];
        #pragma unroll
        for (int mt = 0; mt < 2; ++mt) {
            const int mrow = mbase + wave * 32 + mt * 16 + lq * 4;
            #pragma unroll
            for (int r = 0; r < 4; ++r)
                out[(size_t)(mrow + r) * 512 + n] = f2bf(acc[mt][nt][r] + bias);
        }
    }
}

// ---------------------------------------------------------------------------
// rec5: 8 WGs x 256 thr (4 waves = 1/SIMD, 512-reg budget).
// WG bg owns batches [bg*16,+16), full H=512. Wave owns 8 j-tiles (128 j).
// W: kt 0..11 pinned in VGPRs (8j x 12kt x 4 = 384), kt 12..15 in LDS.
// ---------------------------------------------------------------------------
__global__ __launch_bounds__(256, 1) void rec5_kernel(
    const unsigned short* __restrict__ Wpk,  // [512 frag][64 lane][8] bf16
    const unsigned short* xp,                // [S][B][H] bf16 (aliases hs_out)
    unsigned short* hs_out,                  // [S][B][H] bf16
    float* __restrict__ h_last,              // [B][H] fp32
    int mode)
{
    __shared__ unsigned short h2[2][16 * 512];        // 32 KB
    __shared__ unsigned short wlds[4 * 32 * 64 * 8];  // 128 KB (total 160 KiB)

    const int tid  = threadIdx.x;
    const int lane = tid & 63;
    const int wave = tid >> 6;                 // 0..3
    const int lm   = lane & 15, lq = lane >> 4;
    const int bg   = blockIdx.x;
    const int bb   = bg * 16 + lm;             // this lane's batch column
    const int lmx  = (lm & 7) ^ ((lm >> 1) & 4);   // min-phase swizzle key

    // ---- resident W frags: kt 0..11 for this wave's 8 j-tiles (384 VGPR) ----
    short8 wreg[8][12];
    #pragma unroll
    for (int j = 0; j < 8; ++j) {
        const int jtg = wave * 8 + j;
        #pragma unroll
        for (int kt = 0; kt < 12; ++kt)
            wreg[j][kt] = *(const short8*)(Wpk + ((size_t)(jtg * 16 + kt) * 64 + lane) * 8);
    }
    // Pin so the loads cannot sink into the loop (R3 failure) — and the
    // 1-wave/SIMD budget (512) means they no longer spill (R4 failure).
    #pragma unroll
    for (int j = 0; j < 8; ++j)
        #pragma unroll
        for (int kt = 0; kt < 12; ++kt)
            PIN(wreg[j][kt]);

    // ---- load W kt 12..15 into LDS (layout [ktl][jtg][lane][8]) ----
    for (int i = tid; i < 4 * 32 * 64; i += 256) {
        const int l_  = i & 63;
        const int jg_ = (i >> 6) & 31;
        const int kl_ = i >> 11;              // 0..3
        *(short8*)(wlds + (size_t)i * 8) =
            *(const short8*)(Wpk + ((size_t)(jg_ * 16 + 12 + kl_) * 64 + l_) * 8);
    }

    // ---- zero h buffers ----
    for (int i = tid; i < 2 * 16 * 512; i += 256)
        ((unsigned short*)h2)[i] = 0;
    __syncthreads();

    for (int t = 0; t < 512; ++t) {
        const int p = t & 1;
        const unsigned short* hp = &h2[p][0];       // read h_{t-1}
        unsigned short*       hw = &h2[p ^ 1][0];   // write h_t

        // ---- xp operands for epilogue (issue early, consumed late) ----
        const size_t xrow = ((size_t)t * 128 + bb) * 512;
        ushort4 xv[8];
        #pragma unroll
        for (int j = 0; j < 8; ++j)
            xv[j] = *(const ushort4*)(xp + xrow + (wave * 8 + j) * 16 + lq * 4);

        floatx4 acc[8] = {};

        // ---- kt 0..11 from pinned registers ----
        #pragma unroll
        for (int kt = 0; kt < 12; ++kt) {
            short8 bfr = *(const short8*)(hp + lm * 512 + ((((kt << 2) + lq) ^ lmx) << 3));
            #pragma unroll
            for (int j = 0; j < 8; ++j)
                acc[j] = __builtin_amdgcn_mfma_f32_16x16x32_bf16(wreg[j][kt], bfr, acc[j], 0, 0, 0);
        }
        // ---- kt 12..15 from LDS ----
        #pragma unroll
        for (int ktl = 0; ktl < 4; ++ktl) {
            const int kt = 12 + ktl;
            short8 bfr = *(const short8*)(hp + lm * 512 + ((((kt << 2) + lq) ^ lmx) << 3));
            #pragma unroll
            for (int j = 0; j < 8; ++j) {
                short8 wf = *(const short8*)(wlds + ((size_t)(ktl * 32 + wave * 8 + j) * 64 + lane) * 8);
                acc[j] = __builtin_amdgcn_mfma_f32_16x16x32_bf16(wf, bfr, acc[j], 0, 0, 0);
            }
        }

        // ---- epilogue: j = (wave*8+j)*16 + lq*4 + r, batch = bb ----
        #pragma unroll
        for (int j = 0; j < 8; ++j) {
            const int jb = (wave * 8 + j) * 16 + lq * 4;
            float q0 = tanh_fast(acc[j][0] + bf2f(xv[j].x));
            float q1 = tanh_fast(acc[j][1] + bf2f(xv[j].y));
            float q2 = tanh_fast(acc[j][2] + bf2f(xv[j].z));
            float q3 = tanh_fast(acc[j][3] + bf2f(xv[j].w));
            ushort4 pk;
            pk.x = f2bf(q0); pk.y = f2bf(q1); pk.z = f2bf(q2); pk.w = f2bf(q3);
            // swizzled LDS write: logical granule (jb>>3) stored at ^lmx
            *(ushort4*)(hw + lm * 512 + (((jb >> 3) ^ lmx) << 3) + (jb & 7)) = pk;
            if (mode == 0) {
                *(ushort4*)(hs_out + xrow + jb) = pk;
            } else if (t == 511) {
                float4 o; o.x = q0; o.y = q1; o.z = q2; o.w = q3;
                *(float4*)(h_last + (size_t)bb * 512 + jb) = o;
            }
        }
        __syncthreads();
    }
}

// ---------------------------------------------------------------------------
// head: logits[b][c] = h_last[b][:]·W_out[c][:] + b_out[c]; log_softmax rows.
// ---------------------------------------------------------------------------
__global__ __launch_bounds__(256, 2) void head_kernel(
    const float* __restrict__ hl, const float* __restrict__ Wout,
    const float* __restrict__ bout, float* __restrict__ out)
{
    __shared__ float hrow[512];
    __shared__ float lg[1000];
    __shared__ float red[8];
    const int b = blockIdx.x, tid = threadIdx.x;

    hrow[tid]       = hl[(size_t)b * 512 + tid];
    hrow[tid + 256] = hl[(size_t)b * 512 + 256 + tid];
    __syncthreads();

    float lmax = -1e30f;
    for (int c = tid; c < 1000; c += 256) {
        const float4* w4 = (const float4*)(Wout + (size_t)c * 512);
        float a0 = 0.f, a1 = 0.f, a2 = 0.f, a3 = 0.f;
        #pragma unroll 4
        for (int k = 0; k < 128; ++k) {
            float4 w = w4[k];
            a0 += hrow[4 * k + 0] * w.x;
            a1 += hrow[4 * k + 1] * w.y;
            a2 += hrow[4 * k + 2] * w.z;
            a3 += hrow[4 * k + 3] * w.w;
        }
        float acc = bout[c] + (a0 + a1) + (a2 + a3);
        lg[c] = acc;
        lmax = fmaxf(lmax, acc);
    }
    #pragma unroll
    for (int off = 32; off; off >>= 1) lmax = fmaxf(lmax, __shfl_down(lmax, off, 64));
    if ((tid & 63) == 0) red[tid >> 6] = lmax;
    __syncthreads();
    if (tid == 0) red[4] = fmaxf(fmaxf(red[0], red[1]), fmaxf(red[2], red[3]));
    __syncthreads();
    const float M = red[4];

    float lsum = 0.f;
    for (int c = tid; c < 1000; c += 256) lsum += __expf(lg[c] - M);
    #pragma unroll
    for (int off = 32; off; off >>= 1) lsum += __shfl_down(lsum, off, 64);
    __syncthreads();
    if ((tid & 63) == 0) red[tid >> 6] = lsum;
    __syncthreads();
    if (tid == 0) red[5] = M + __logf(red[0] + red[1] + red[2] + red[3]);
    __syncthreads();
    const float lse = red[5];

    for (int c = tid; c < 1000; c += 256)
        out[(size_t)b * 1000 + c] = lg[c] - lse;
}

// ---------------------------------------------------------------------------
extern "C" void kernel_launch(void* const* d_in, const int* in_sizes, int n_in,
                              void* d_out, int out_size, void* d_ws, size_t ws_size,
                              hipStream_t stream)
{
    const float* x    = (const float*)d_in[0];
    const float* Wih0 = (const float*)d_in[1];
    const float* Whh0 = (const float*)d_in[2];
    const float* bih0 = (const float*)d_in[3];
    const float* bhh0 = (const float*)d_in[4];
    const float* Wih1 = (const float*)d_in[5];
    const float* Whh1 = (const float*)d_in[6];
    const float* bih1 = (const float*)d_in[7];
    const float* bhh1 = (const float*)d_in[8];
    const float* Wout = (const float*)d_in[9];
    const float* bout = (const float*)d_in[10];
    float* out = (float*)d_out;

    char* ws = (char*)d_ws;
    unsigned short* bufA = (unsigned short*)ws;                             // 64 MB
    unsigned short* bufB = (unsigned short*)(ws + (size_t)64 * 1024 * 1024);
    unsigned short* Wpk0 = bufB;                                            // 512 KB (dead after rec0)
    unsigned short* Wpk1 = bufA;                                            // 512 KB (bufA head, dead after proj1)
    float*         hlast = (float*)(ws + (size_t)1 * 1024 * 1024);          // 256 KB @ bufA+1MB

    const dim3 pgrid(8, 512);

    prepack_kernel<<<128, 256, 0, stream>>>(Whh0, Wpk0);
    proj_kernel<128, 0><<<pgrid, 256, 0, stream>>>((const void*)x, Wih0, bih0, bhh0, bufA);
    rec5_kernel<<<8, 256, 0, stream>>>(Wpk0, bufA, bufA, hlast, 0);

    proj_kernel<512, 1><<<pgrid, 256, 0, stream>>>((const void*)bufA, Wih1, bih1, bhh1, bufB);
    prepack_kernel<<<128, 256, 0, stream>>>(Whh1, Wpk1);
    rec5_kernel<<<8, 256, 0, stream>>>(Wpk1, bufB, bufB, hlast, 1);

    head_kernel<<<128, 256, 0, stream>>>(hlast, Wout, bout, out);
}

// Round 6
// 3689.372 us; speedup vs baseline: 1.0423x; 1.0423x over previous
//
#include <hip/hip_runtime.h>

// ============================================================================
// 2-layer tanh RNN (B=128,S=512,IN=128,H=512) + linear head (C=1000) + logsoftmax
//
// Round-6: R5 structure, register CLASS fix.
//   R5 failure: 384 W values pinned "+v" but arch VGPRs cap at 256 (v0-v255);
//   the 512-reg/wave budget at 1 wave/SIMD is 256 VGPR + 256 AGPR (unified
//   file). Result: scratch spill, re-read every step (VGPR_Count=256, 1886us).
//   Fix: split W across classes — MFMA reads A-operands straight from AGPRs
//   on gfx950 (cdna4_isa §10).
//     kt 0..7  -> wrega[8][8] pinned "+a"  (256 AGPR, fills the AGPR file)
//     kt 8..11 -> wregv[8][4] pinned "+v"  (128 VGPR)
//     kt 12..15-> LDS (128 KB, loaded once)
//   VGPR working set ~226 <= 256 -> no spill, zero per-step W re-fetch.
//   - 8 WGs x 256 thr (4 waves, 1/SIMD). WG owns 16 batches, full H=512.
//   - h: LDS [2][16][512] bf16 double buffer, min-phase swizzle.
//   - 1 __syncthreads per step. LDS = 163840 B (exactly 160 KiB).
//
// ws layout: bufA = ws (64 MB): xp0/hs0 in place; Wpk1 at head later;
//            hlast @ ws+1MB; bufB = ws+64MB: Wpk0 at head, later xp1.
// ============================================================================

using short8  = __attribute__((ext_vector_type(8))) short;
using floatx4 = __attribute__((ext_vector_type(4))) float;

#define DEV static __device__ __forceinline__
#define PINV(x) asm volatile("" : "+v"(x))
#define PINA(x) asm volatile("" : "+a"(x))

DEV unsigned short f2bf(float f) {
    union { float f; unsigned u; } v; v.f = f;
    unsigned r = (v.u + 0x7fffu + ((v.u >> 16) & 1u)) >> 16;
    return (unsigned short)r;
}
DEV float bf2f(unsigned short h) {
    union { unsigned u; float f; } v; v.u = ((unsigned)h) << 16;
    return v.f;
}
DEV float tanh_fast(float x) {
    // tanh(x) = 1 - 2/(e^{2x}+1); saturates correctly at +/-inf
    float e = __expf(2.0f * x);
    return 1.0f - 2.0f * __builtin_amdgcn_rcpf(e + 1.0f);
}

// ---------------------------------------------------------------------------
// prepack: W_hh fp32 [512][512] -> bf16 A-frag order.
// frag = jtg*16 + kt; lane holds j = jtg*16+(lane&15), k = kt*32+(lane>>4)*8+e.
// ---------------------------------------------------------------------------
__global__ void prepack_kernel(const float* __restrict__ W,
                               unsigned short* __restrict__ Wpk)
{
    const int gid  = blockIdx.x * 256 + threadIdx.x;   // 0..32767
    const int lane = gid & 63;
    const int frag = gid >> 6;                         // 0..511
    const int kt   = frag & 15;
    const int jtg  = frag >> 4;
    const int j    = jtg * 16 + (lane & 15);
    const int k    = kt * 32 + (lane >> 4) * 8;
    const float* src = W + (size_t)j * 512 + k;
    float4 a = *(const float4*)(src);
    float4 b = *(const float4*)(src + 4);
    short8 p;
    p[0]=(short)f2bf(a.x); p[1]=(short)f2bf(a.y);
    p[2]=(short)f2bf(a.z); p[3]=(short)f2bf(a.w);
    p[4]=(short)f2bf(b.x); p[5]=(short)f2bf(b.y);
    p[6]=(short)f2bf(b.z); p[7]=(short)f2bf(b.w);
    *(short8*)(Wpk + (size_t)gid * 8) = p;
}

// ---------------------------------------------------------------------------
// proj: out[m=t*128+b][n] = bf16( A[m][:]·W[n][:] + b1[n]+b2[n] )  (unchanged)
// ---------------------------------------------------------------------------
template <int K, int MODE>
__global__ __launch_bounds__(256, 2) void proj_kernel(
    const void* __restrict__ Aptr, const float* __restrict__ W,
    const float* __restrict__ b1, const float* __restrict__ b2,
    unsigned short* __restrict__ out)
{
    constexpr int LDA = 40;
    __shared__ unsigned short As[128 * LDA];
    __shared__ unsigned short Ws[64 * LDA];

    const int tid  = threadIdx.x;
    const int lane = tid & 63, wave = tid >> 6;
    const int lm   = lane & 15, lq = lane >> 4;
    const int nbase = blockIdx.x * 64;
    const int mtile = blockIdx.y;
    const int mbase = mtile * 128;

    floatx4 acc[2][4] = {};

    const int ar = tid >> 1, ak = (tid & 1) * 16;
    const int wr = tid >> 2, wk = (tid & 3) * 8;

    for (int k0 = 0; k0 < K; k0 += 32) {
        if (MODE == 0) {
            const float* x   = (const float*)Aptr;
            const float* src = x + ((size_t)ar * 512 + mtile) * 128 + (k0 + ak);
            float4 f0 = *(const float4*)(src + 0);
            float4 f1 = *(const float4*)(src + 4);
            float4 f2 = *(const float4*)(src + 8);
            float4 f3 = *(const float4*)(src + 12);
            unsigned short* d = As + ar * LDA + ak;
            d[0]=f2bf(f0.x); d[1]=f2bf(f0.y); d[2]=f2bf(f0.z); d[3]=f2bf(f0.w);
            d[4]=f2bf(f1.x); d[5]=f2bf(f1.y); d[6]=f2bf(f1.z); d[7]=f2bf(f1.w);
            d[8]=f2bf(f2.x); d[9]=f2bf(f2.y); d[10]=f2bf(f2.z); d[11]=f2bf(f2.w);
            d[12]=f2bf(f3.x); d[13]=f2bf(f3.y); d[14]=f2bf(f3.z); d[15]=f2bf(f3.w);
        } else {
            const unsigned short* h =
                (const unsigned short*)Aptr + (size_t)(mbase + ar) * K + k0 + ak;
            short8 v0 = *(const short8*)(h);
            short8 v1 = *(const short8*)(h + 8);
            *(short8*)(As + ar * LDA + ak)     = v0;
            *(short8*)(As + ar * LDA + ak + 8) = v1;
        }
        {
            const float* src = W + (size_t)(nbase + wr) * K + k0 + wk;
            float4 f0 = *(const float4*)(src);
            float4 f1 = *(const float4*)(src + 4);
            unsigned short* d = Ws + wr * LDA + wk;
            d[0]=f2bf(f0.x); d[1]=f2bf(f0.y); d[2]=f2bf(f0.z); d[3]=f2bf(f0.w);
            d[4]=f2bf(f1.x); d[5]=f2bf(f1.y); d[6]=f2bf(f1.z); d[7]=f2bf(f1.w);
        }
        __syncthreads();

        short8 af0 = *(const short8*)(As + (wave * 32 +  0 + lm) * LDA + lq * 8);
        short8 af1 = *(const short8*)(As + (wave * 32 + 16 + lm) * LDA + lq * 8);
        #pragma unroll
        for (int nt = 0; nt < 4; ++nt) {
            short8 bf = *(const short8*)(Ws + (nt * 16 + lm) * LDA + lq * 8);
            acc[0][nt] = __builtin_amdgcn_mfma_f32_16x16x32_bf16(af0, bf, acc[0][nt], 0, 0, 0);
            acc[1][nt] = __builtin_amdgcn_mfma_f32_16x16x32_bf16(af1, bf, acc[1][nt], 0, 0, 0);
        }
        __syncthreads();
    }

    #pragma unroll
    for (int nt = 0; nt < 4; ++nt) {
        const int n = nbase + nt * 16 + lm;
        const float bias = b1[n] + b2[n];
        #pragma unroll
        for (int mt = 0; mt < 2; ++mt) {
            const int mrow = mbase + wave * 32 + mt * 16 + lq * 4;
            #pragma unroll
            for (int r = 0; r < 4; ++r)
                out[(size_t)(mrow + r) * 512 + n] = f2bf(acc[mt][nt][r] + bias);
        }
    }
}

// ---------------------------------------------------------------------------
// rec6: 8 WGs x 256 thr (4 waves = 1/SIMD, 512-reg unified budget).
// WG bg owns batches [bg*16,+16), full H=512. Wave owns 8 j-tiles (128 j).
// W: kt 0..7 pinned in AGPRs (256), kt 8..11 pinned in VGPRs (128),
//    kt 12..15 in LDS (128 KB).
// ---------------------------------------------------------------------------
__global__ __launch_bounds__(256, 1) void rec6_kernel(
    const unsigned short* __restrict__ Wpk,  // [512 frag][64 lane][8] bf16
    const unsigned short* xp,                // [S][B][H] bf16 (aliases hs_out)
    unsigned short* hs_out,                  // [S][B][H] bf16
    float* __restrict__ h_last,              // [B][H] fp32
    int mode)
{
    __shared__ unsigned short h2[2][16 * 512];        // 32 KB
    __shared__ unsigned short wlds[4 * 32 * 64 * 8];  // 128 KB (total 160 KiB)

    const int tid  = threadIdx.x;
    const int lane = tid & 63;
    const int wave = tid >> 6;                 // 0..3
    const int lm   = lane & 15, lq = lane >> 4;
    const int bg   = blockIdx.x;
    const int bb   = bg * 16 + lm;             // this lane's batch column
    const int lmx  = (lm & 7) ^ ((lm >> 1) & 4);   // min-phase swizzle key

    // ---- resident W frags for this wave's 8 j-tiles ----
    // kt 0..7 -> AGPR class (256 regs), kt 8..11 -> VGPR class (128 regs)
    short8 wrega[8][8];
    short8 wregv[8][4];
    #pragma unroll
    for (int j = 0; j < 8; ++j) {
        const int jtg = wave * 8 + j;
        #pragma unroll
        for (int kt = 0; kt < 8; ++kt)
            wrega[j][kt] = *(const short8*)(Wpk + ((size_t)(jtg * 16 + kt) * 64 + lane) * 8);
        #pragma unroll
        for (int kt = 0; kt < 4; ++kt)
            wregv[j][kt] = *(const short8*)(Wpk + ((size_t)(jtg * 16 + 8 + kt) * 64 + lane) * 8);
    }
    // Pin: loads cannot sink into the loop (R3 failure); "+a" places the
    // big half in the AGPR file so the VGPR class isn't overcommitted (R5
    // failure — arch VGPRs cap at 256). MFMA reads A straight from AGPRs.
    #pragma unroll
    for (int j = 0; j < 8; ++j) {
        #pragma unroll
        for (int kt = 0; kt < 8; ++kt)
            PINA(wrega[j][kt]);
        #pragma unroll
        for (int kt = 0; kt < 4; ++kt)
            PINV(wregv[j][kt]);
    }

    // ---- load W kt 12..15 into LDS (layout [ktl][jtg][lane][8]) ----
    for (int i = tid; i < 4 * 32 * 64; i += 256) {
        const int l_  = i & 63;
        const int jg_ = (i >> 6) & 31;
        const int kl_ = i >> 11;              // 0..3
        *(short8*)(wlds + (size_t)i * 8) =
            *(const short8*)(Wpk + ((size_t)(jg_ * 16 + 12 + kl_) * 64 + l_) * 8);
    }

    // ---- zero h buffers ----
    for (int i = tid; i < 2 * 16 * 512; i += 256)
        ((unsigned short*)h2)[i] = 0;
    __syncthreads();

    for (int t = 0; t < 512; ++t) {
        const int p = t & 1;
        const unsigned short* hp = &h2[p][0];       // read h_{t-1}
        unsigned short*       hw = &h2[p ^ 1][0];   // write h_t

        // ---- xp operands for epilogue (issue early, consumed late) ----
        const size_t xrow = ((size_t)t * 128 + bb) * 512;
        ushort4 xv[8];
        #pragma unroll
        for (int j = 0; j < 8; ++j)
            xv[j] = *(const ushort4*)(xp + xrow + (wave * 8 + j) * 16 + lq * 4);

        floatx4 acc[8] = {};

        // ---- kt 0..7 from AGPR-pinned registers ----
        #pragma unroll
        for (int kt = 0; kt < 8; ++kt) {
            short8 bfr = *(const short8*)(hp + lm * 512 + ((((kt << 2) + lq) ^ lmx) << 3));
            #pragma unroll
            for (int j = 0; j < 8; ++j)
                acc[j] = __builtin_amdgcn_mfma_f32_16x16x32_bf16(wrega[j][kt], bfr, acc[j], 0, 0, 0);
        }
        // ---- kt 8..11 from VGPR-pinned registers ----
        #pragma unroll
        for (int kt = 0; kt < 4; ++kt) {
            const int ktg = 8 + kt;
            short8 bfr = *(const short8*)(hp + lm * 512 + ((((ktg << 2) + lq) ^ lmx) << 3));
            #pragma unroll
            for (int j = 0; j < 8; ++j)
                acc[j] = __builtin_amdgcn_mfma_f32_16x16x32_bf16(wregv[j][kt], bfr, acc[j], 0, 0, 0);
        }
        // ---- kt 12..15 from LDS ----
        #pragma unroll
        for (int ktl = 0; ktl < 4; ++ktl) {
            const int kt = 12 + ktl;
            short8 bfr = *(const short8*)(hp + lm * 512 + ((((kt << 2) + lq) ^ lmx) << 3));
            #pragma unroll
            for (int j = 0; j < 8; ++j) {
                short8 wf = *(const short8*)(wlds + ((size_t)(ktl * 32 + wave * 8 + j) * 64 + lane) * 8);
                acc[j] = __builtin_amdgcn_mfma_f32_16x16x32_bf16(wf, bfr, acc[j], 0, 0, 0);
            }
        }

        // ---- epilogue: j = (wave*8+j)*16 + lq*4 + r, batch = bb ----
        #pragma unroll
        for (int j = 0; j < 8; ++j) {
            const int jb = (wave * 8 + j) * 16 + lq * 4;
            float q0 = tanh_fast(acc[j][0] + bf2f(xv[j].x));
            float q1 = tanh_fast(acc[j][1] + bf2f(xv[j].y));
            float q2 = tanh_fast(acc[j][2] + bf2f(xv[j].z));
            float q3 = tanh_fast(acc[j][3] + bf2f(xv[j].w));
            ushort4 pk;
            pk.x = f2bf(q0); pk.y = f2bf(q1); pk.z = f2bf(q2); pk.w = f2bf(q3);
            // swizzled LDS write: logical granule (jb>>3) stored at ^lmx
            *(ushort4*)(hw + lm * 512 + (((jb >> 3) ^ lmx) << 3) + (jb & 7)) = pk;
            if (mode == 0) {
                *(ushort4*)(hs_out + xrow + jb) = pk;
            } else if (t == 511) {
                float4 o; o.x = q0; o.y = q1; o.z = q2; o.w = q3;
                *(float4*)(h_last + (size_t)bb * 512 + jb) = o;
            }
        }
        __syncthreads();
    }
}

// ---------------------------------------------------------------------------
// head: logits[b][c] = h_last[b][:]·W_out[c][:] + b_out[c]; log_softmax rows.
// ---------------------------------------------------------------------------
__global__ __launch_bounds__(256, 2) void head_kernel(
    const float* __restrict__ hl, const float* __restrict__ Wout,
    const float* __restrict__ bout, float* __restrict__ out)
{
    __shared__ float hrow[512];
    __shared__ float lg[1000];
    __shared__ float red[8];
    const int b = blockIdx.x, tid = threadIdx.x;

    hrow[tid]       = hl[(size_t)b * 512 + tid];
    hrow[tid + 256] = hl[(size_t)b * 512 + 256 + tid];
    __syncthreads();

    float lmax = -1e30f;
    for (int c = tid; c < 1000; c += 256) {
        const float4* w4 = (const float4*)(Wout + (size_t)c * 512);
        float a0 = 0.f, a1 = 0.f, a2 = 0.f, a3 = 0.f;
        #pragma unroll 4
        for (int k = 0; k < 128; ++k) {
            float4 w = w4[k];
            a0 += hrow[4 * k + 0] * w.x;
            a1 += hrow[4 * k + 1] * w.y;
            a2 += hrow[4 * k + 2] * w.z;
            a3 += hrow[4 * k + 3] * w.w;
        }
        float acc = bout[c] + (a0 + a1) + (a2 + a3);
        lg[c] = acc;
        lmax = fmaxf(lmax, acc);
    }
    #pragma unroll
    for (int off = 32; off; off >>= 1) lmax = fmaxf(lmax, __shfl_down(lmax, off, 64));
    if ((tid & 63) == 0) red[tid >> 6] = lmax;
    __syncthreads();
    if (tid == 0) red[4] = fmaxf(fmaxf(red[0], red[1]), fmaxf(red[2], red[3]));
    __syncthreads();
    const float M = red[4];

    float lsum = 0.f;
    for (int c = tid; c < 1000; c += 256) lsum += __expf(lg[c] - M);
    #pragma unroll
    for (int off = 32; off; off >>= 1) lsum += __shfl_down(lsum, off, 64);
    __syncthreads();
    if ((tid & 63) == 0) red[tid >> 6] = lsum;
    __syncthreads();
    if (tid == 0) red[5] = M + __logf(red[0] + red[1] + red[2] + red[3]);
    __syncthreads();
    const float lse = red[5];

    for (int c = tid; c < 1000; c += 256)
        out[(size_t)b * 1000 + c] = lg[c] - lse;
}

// ---------------------------------------------------------------------------
extern "C" void kernel_launch(void* const* d_in, const int* in_sizes, int n_in,
                              void* d_out, int out_size, void* d_ws, size_t ws_size,
                              hipStream_t stream)
{
    const float* x    = (const float*)d_in[0];
    const float* Wih0 = (const float*)d_in[1];
    const float* Whh0 = (const float*)d_in[2];
    const float* bih0 = (const float*)d_in[3];
    const float* bhh0 = (const float*)d_in[4];
    const float* Wih1 = (const float*)d_in[5];
    const float* Whh1 = (const float*)d_in[6];
    const float* bih1 = (const float*)d_in[7];
    const float* bhh1 = (const float*)d_in[8];
    const float* Wout = (const float*)d_in[9];
    const float* bout = (const float*)d_in[10];
    float* out = (float*)d_out;

    char* ws = (char*)d_ws;
    unsigned short* bufA = (unsigned short*)ws;                             // 64 MB
    unsigned short* bufB = (unsigned short*)(ws + (size_t)64 * 1024 * 1024);
    unsigned short* Wpk0 = bufB;                                            // 512 KB (dead after rec0)
    unsigned short* Wpk1 = bufA;                                            // 512 KB (bufA head, dead after proj1)
    float*         hlast = (float*)(ws + (size_t)1 * 1024 * 1024);          // 256 KB @ bufA+1MB

    const dim3 pgrid(8, 512);

    prepack_kernel<<<128, 256, 0, stream>>>(Whh0, Wpk0);
    proj_kernel<128, 0><<<pgrid, 256, 0, stream>>>((const void*)x, Wih0, bih0, bhh0, bufA);
    rec6_kernel<<<8, 256, 0, stream>>>(Wpk0, bufA, bufA, hlast, 0);

    proj_kernel<512, 1><<<pgrid, 256, 0, stream>>>((const void*)bufA, Wih1, bih1, bhh1, bufB);
    prepack_kernel<<<128, 256, 0, stream>>>(Whh1, Wpk1);
    rec6_kernel<<<8, 256, 0, stream>>>(Wpk1, bufB, bufB, hlast, 1);

    head_kernel<<<128, 256, 0, stream>>>(hlast, Wout, bout, out);
}

// Round 7
// 2136.722 us; speedup vs baseline: 1.7997x; 1.7267x over previous
//
#include <hip/hip_runtime.h>

// ============================================================================
// 2-layer tanh RNN (B=128,S=512,IN=128,H=512) + linear head (C=1000) + logsoftmax
//
// Round-7: i8 recurrence.
//   R6 evidence: no spill, W resident, but step = sum of LDS pipe (208 KB/step,
//   ~2500 cyc — half of it W-from-LDS), MFMA 128/wave, VALU ~2400/CU, plus
//   vmcnt(0) drain at every __syncthreads. Fix all four:
//   - W_hh -> int8, per-row scale. mfma_i32_16x16x64_i8: A-frag 4 regs ->
//     FULL W slice (8 jtg x 8 kt) = exactly 256 AGPRs. No W in LDS at all.
//     MFMA count halves (64/wave/step).
//   - h state i8 in LDS [2][16][512] = 16 KB; 16B-granule XOR-lm swizzle
//     (2-way on read b128 and write b32 = free).
//   - CK barrier: s_waitcnt lgkmcnt(0) + s_barrier (no vmcnt drain; xp loads
//     and hs_out stores stay in flight across the barrier).
//   - Epilogue: dequant = cvt+fma; i8 pack via 1.5*2^23 magic fma + v_perm;
//     bf16 hs_out pack via v_perm truncation.
//   - 8 WGs x 256 thr (4 waves, 1/SIMD). WG owns 16 batches, full H=512.
//
// ws layout: bufA = ws (64 MB): xp0/hs0 in place; later Wq1 [0,256K) +
//            sc1 [256K,258K) + hlast @ +1MB. bufB = ws+64MB: Wq0/sc0 at head
//            (dead after rec0), later xp1.
// ============================================================================

using short8  = __attribute__((ext_vector_type(8))) short;
using floatx4 = __attribute__((ext_vector_type(4))) float;
using i32x4   = __attribute__((ext_vector_type(4))) int;
using f32x4   = __attribute__((ext_vector_type(4))) float;

#define DEV static __device__ __forceinline__
#define PINA(x) asm volatile("" : "+a"(x))
#define PINV(x) asm volatile("" : "+v"(x))

DEV void lds_barrier() {
    // LDS-only barrier: do NOT drain vmcnt (global stores/loads keep flying).
    asm volatile("s_waitcnt lgkmcnt(0)\n\ts_barrier" ::: "memory");
}

DEV unsigned short f2bf(float f) {
    union { float f; unsigned u; } v; v.f = f;
    unsigned r = (v.u + 0x7fffu + ((v.u >> 16) & 1u)) >> 16;
    return (unsigned short)r;
}
DEV float bf2f(unsigned short h) {
    union { unsigned u; float f; } v; v.u = ((unsigned)h) << 16;
    return v.f;
}
DEV float tanh_fast(float x) {
    // tanh(x) = 1 - 2/(exp2(x*2*log2e)+1); saturates correctly at +/-inf
    float e = __builtin_amdgcn_exp2f(x * 2.8853900817779268f);
    return fmaf(-2.0f, __builtin_amdgcn_rcpf(e + 1.0f), 1.0f);
}

// ---------------------------------------------------------------------------
// packi8: one block (64 thr) per W row j. Row absmax -> per-row scale;
// quantize to i8 in A-frag layout for mfma_i32_16x16x64_i8:
//   frag (jtg, kt): lane = lq*16+lm holds j = jtg*16+lm, k = kt*64+lq*16+e.
// sc2[j] = mx_j / 127^2 (dequant constant).
// ---------------------------------------------------------------------------
__global__ __launch_bounds__(64) void packi8_kernel(
    const float* __restrict__ W, signed char* __restrict__ Wq,
    float* __restrict__ sc2)
{
    const int j = blockIdx.x;            // 0..511
    const int t = threadIdx.x;           // 0..63
    const float* row = W + (size_t)j * 512;

    float4 a = *(const float4*)(row + t * 8);
    float4 b = *(const float4*)(row + t * 8 + 4);
    float m = fmaxf(fmaxf(fabsf(a.x), fabsf(a.y)), fmaxf(fabsf(a.z), fabsf(a.w)));
    m = fmaxf(m, fmaxf(fmaxf(fabsf(b.x), fabsf(b.y)), fmaxf(fabsf(b.z), fabsf(b.w))));
    #pragma unroll
    for (int off = 32; off; off >>= 1) m = fmaxf(m, __shfl_down(m, off, 64));
    m = __shfl(m, 0, 64);
    if (t == 0) sc2[j] = m * (1.0f / (127.f * 127.f));

    if (t < 32) {
        const int kt = t >> 2, lq = t & 3;
        const int jtg = j >> 4, lm = j & 15;
        const float r = 127.f / m;
        int w4[4];
        #pragma unroll
        for (int w = 0; w < 4; ++w) {
            int v = 0;
            #pragma unroll
            for (int e = 0; e < 4; ++e) {
                int q = __float2int_rn(row[kt * 64 + lq * 16 + w * 4 + e] * r);
                v |= (q & 255) << (8 * e);
            }
            w4[w] = v;
        }
        i32x4 pk; pk[0] = w4[0]; pk[1] = w4[1]; pk[2] = w4[2]; pk[3] = w4[3];
        *(i32x4*)(Wq + ((size_t)((jtg * 8 + kt) * 64 + lq * 16 + lm)) * 16) = pk;
    }
}

// ---------------------------------------------------------------------------
// proj: out[m=t*128+b][n] = bf16( A[m][:]·W[n][:] + b1[n]+b2[n] )  (unchanged)
// ---------------------------------------------------------------------------
template <int K, int MODE>
__global__ __launch_bounds__(256, 2) void proj_kernel(
    const void* __restrict__ Aptr, const float* __restrict__ W,
    const float* __restrict__ b1, const float* __restrict__ b2,
    unsigned short* __restrict__ out)
{
    constexpr int LDA = 40;
    __shared__ unsigned short As[128 * LDA];
    __shared__ unsigned short Ws[64 * LDA];

    const int tid  = threadIdx.x;
    const int lane = tid & 63, wave = tid >> 6;
    const int lm   = lane & 15, lq = lane >> 4;
    const int nbase = blockIdx.x * 64;
    const int mtile = blockIdx.y;
    const int mbase = mtile * 128;

    floatx4 acc[2][4] = {};

    const int ar = tid >> 1, ak = (tid & 1) * 16;
    const int wr = tid >> 2, wk = (tid & 3) * 8;

    for (int k0 = 0; k0 < K; k0 += 32) {
        if (MODE == 0) {
            const float* x   = (const float*)Aptr;
            const float* src = x + ((size_t)ar * 512 + mtile) * 128 + (k0 + ak);
            float4 f0 = *(const float4*)(src + 0);
            float4 f1 = *(const float4*)(src + 4);
            float4 f2 = *(const float4*)(src + 8);
            float4 f3 = *(const float4*)(src + 12);
            unsigned short* d = As + ar * LDA + ak;
            d[0]=f2bf(f0.x); d[1]=f2bf(f0.y); d[2]=f2bf(f0.z); d[3]=f2bf(f0.w);
            d[4]=f2bf(f1.x); d[5]=f2bf(f1.y); d[6]=f2bf(f1.z); d[7]=f2bf(f1.w);
            d[8]=f2bf(f2.x); d[9]=f2bf(f2.y); d[10]=f2bf(f2.z); d[11]=f2bf(f2.w);
            d[12]=f2bf(f3.x); d[13]=f2bf(f3.y); d[14]=f2bf(f3.z); d[15]=f2bf(f3.w);
        } else {
            const unsigned short* h =
                (const unsigned short*)Aptr + (size_t)(mbase + ar) * K + k0 + ak;
            short8 v0 = *(const short8*)(h);
            short8 v1 = *(const short8*)(h + 8);
            *(short8*)(As + ar * LDA + ak)     = v0;
            *(short8*)(As + ar * LDA + ak + 8) = v1;
        }
        {
            const float* src = W + (size_t)(nbase + wr) * K + k0 + wk;
            float4 f0 = *(const float4*)(src);
            float4 f1 = *(const float4*)(src + 4);
            unsigned short* d = Ws + wr * LDA + wk;
            d[0]=f2bf(f0.x); d[1]=f2bf(f0.y); d[2]=f2bf(f0.z); d[3]=f2bf(f0.w);
            d[4]=f2bf(f1.x); d[5]=f2bf(f1.y); d[6]=f2bf(f1.z); d[7]=f2bf(f1.w);
        }
        __syncthreads();

        short8 af0 = *(const short8*)(As + (wave * 32 +  0 + lm) * LDA + lq * 8);
        short8 af1 = *(const short8*)(As + (wave * 32 + 16 + lm) * LDA + lq * 8);
        #pragma unroll
        for (int nt = 0; nt < 4; ++nt) {
            short8 bf = *(const short8*)(Ws + (nt * 16 + lm) * LDA + lq * 8);
            acc[0][nt] = __builtin_amdgcn_mfma_f32_16x16x32_bf16(af0, bf, acc[0][nt], 0, 0, 0);
            acc[1][nt] = __builtin_amdgcn_mfma_f32_16x16x32_bf16(af1, bf, acc[1][nt], 0, 0, 0);
        }
        __syncthreads();
    }

    #pragma unroll
    for (int nt = 0; nt < 4; ++nt) {
        const int n = nbase + nt * 16 + lm;
        const float bias = b1[n] + b2[n];
        #pragma unroll
        for (int mt = 0; mt < 2; ++mt) {
            const int mrow = mbase + wave * 32 + mt * 16 + lq * 4;
            #pragma unroll
            for (int r = 0; r < 4; ++r)
                out[(size_t)(mrow + r) * 512 + n] = f2bf(acc[mt][nt][r] + bias);
        }
    }
}

// ---------------------------------------------------------------------------
// rec7: 8 WGs x 256 thr (4 waves, 1/SIMD). WG bg owns batches [bg*16,+16),
// full H=512; wave owns 8 j-tiles. Full W_hh(i8) in 256 AGPRs.
// h state: i8 LDS [2][16 b][512 j], 16B-granule swizzle g' = g ^ lm.
// MODE 0: store h_t bf16 to hs_out (in-place over xp, same thread+addr).
// MODE 1: store t=511 fp32 to h_last.
// ---------------------------------------------------------------------------
template <int MODE>
__global__ __launch_bounds__(256, 1) void rec7_kernel(
    const signed char* __restrict__ Wq,   // [32 jtg][8 kt][64 lane][16] i8
    const float* __restrict__ sc2,        // [512] row scale / 127^2
    const unsigned short* xp,             // [S][B][H] bf16 (aliases hs_out)
    unsigned short* hs_out,               // [S][B][H] bf16
    float* __restrict__ h_last)           // [B][H] fp32
{
    __shared__ unsigned char h2[2][16 * 512];   // 16 KB

    const int tid  = threadIdx.x;
    const int lane = tid & 63;
    const int wave = tid >> 6;              // 0..3
    const int lm   = lane & 15, lq = lane >> 4;
    const int bg   = blockIdx.x;
    const int bb   = bg * 16 + lm;

    // ---- full W slice in AGPRs: 8 jtg x 8 kt x int4 = 256 AGPRs ----
    i32x4 wa[8][8];
    #pragma unroll
    for (int j = 0; j < 8; ++j) {
        const int jtg = wave * 8 + j;
        #pragma unroll
        for (int kt = 0; kt < 8; ++kt)
            wa[j][kt] = *(const i32x4*)(Wq + ((size_t)((jtg * 8 + kt) * 64 + lane)) * 16);
    }
    #pragma unroll
    for (int j = 0; j < 8; ++j)
        #pragma unroll
        for (int kt = 0; kt < 8; ++kt)
            PINA(wa[j][kt]);

    // ---- per-lane dequant scales (j = jtg*16 + lq*4 + r), pinned ----
    f32x4 sc[8];
    #pragma unroll
    for (int j = 0; j < 8; ++j)
        sc[j] = *(const f32x4*)(sc2 + (wave * 8 + j) * 16 + lq * 4);
    #pragma unroll
    for (int j = 0; j < 8; ++j) PINV(sc[j]);

    // ---- zero h buffers ----
    for (int i = tid; i < 4096; i += 256) ((int*)h2)[i] = 0;
    __syncthreads();

    for (int t = 0; t < 512; ++t) {
        unsigned char* hp = &h2[t & 1][0];
        unsigned char* hw = &h2[(t & 1) ^ 1][0];

        // ---- B-frags: h_{t-1} i8, swizzled granules ----
        i32x4 bfr[8];
        #pragma unroll
        for (int kt = 0; kt < 8; ++kt) {
            const int g = (kt * 4 + lq) ^ lm;        // 16B granule
            bfr[kt] = *(const i32x4*)(hp + lm * 512 + g * 16);
        }

        // ---- xp prefetch (consumed in epilogue) ----
        const size_t xrow = ((size_t)t * 128 + bb) * 512;
        ushort4 xv[8];
        #pragma unroll
        for (int j = 0; j < 8; ++j)
            xv[j] = *(const ushort4*)(xp + xrow + (wave * 8 + j) * 16 + lq * 4);

        // ---- MFMA: 8 j-tiles x 8 kt ----
        i32x4 acc[8];
        const i32x4 z4 = {0, 0, 0, 0};
        #pragma unroll
        for (int j = 0; j < 8; ++j) {
            acc[j] = __builtin_amdgcn_mfma_i32_16x16x64_i8(wa[j][0], bfr[0], z4, 0, 0, 0);
            #pragma unroll
            for (int kt = 1; kt < 8; ++kt)
                acc[j] = __builtin_amdgcn_mfma_i32_16x16x64_i8(wa[j][kt], bfr[kt], acc[j], 0, 0, 0);
        }

        // ---- epilogue ----
        #pragma unroll
        for (int j = 0; j < 8; ++j) {
            const int jtg = wave * 8 + j;
            const int jb  = jtg * 16 + lq * 4;
            float q0 = tanh_fast(fmaf((float)acc[j][0], sc[j][0], bf2f(xv[j].x)));
            float q1 = tanh_fast(fmaf((float)acc[j][1], sc[j][1], bf2f(xv[j].y)));
            float q2 = tanh_fast(fmaf((float)acc[j][2], sc[j][2], bf2f(xv[j].z)));
            float q3 = tanh_fast(fmaf((float)acc[j][3], sc[j][3], bf2f(xv[j].w)));

            // i8 quantize via magic fma (RNE, low byte = int8) + v_perm pack
            unsigned m0 = __float_as_uint(fmaf(q0, 127.f, 12582912.f));
            unsigned m1 = __float_as_uint(fmaf(q1, 127.f, 12582912.f));
            unsigned m2 = __float_as_uint(fmaf(q2, 127.f, 12582912.f));
            unsigned m3 = __float_as_uint(fmaf(q3, 127.f, 12582912.f));
            unsigned lo = __builtin_amdgcn_perm(m1, m0, 0x00000400u);
            unsigned hi = __builtin_amdgcn_perm(m3, m2, 0x00000400u);
            unsigned qb = __builtin_amdgcn_perm(hi, lo, 0x05040100u);
            *(unsigned*)(hw + lm * 512 + ((jtg ^ lm) << 4) + lq * 4) = qb;

            if (MODE == 0) {
                // bf16 truncation pack (hs_out feeds proj1 once; bias ~2^-9)
                uint2 st;
                st.x = __builtin_amdgcn_perm(__float_as_uint(q1), __float_as_uint(q0), 0x07060302u);
                st.y = __builtin_amdgcn_perm(__float_as_uint(q3), __float_as_uint(q2), 0x07060302u);
                *(uint2*)(hs_out + xrow + jb) = st;
            } else if (t == 511) {
                float4 o; o.x = q0; o.y = q1; o.z = q2; o.w = q3;
                *(float4*)(h_last + (size_t)bb * 512 + jb) = o;
            }
        }
        lds_barrier();
    }
}

// ---------------------------------------------------------------------------
// head: logits[b][c] = h_last[b][:]·W_out[c][:] + b_out[c]; log_softmax rows.
// ---------------------------------------------------------------------------
__global__ __launch_bounds__(256, 2) void head_kernel(
    const float* __restrict__ hl, const float* __restrict__ Wout,
    const float* __restrict__ bout, float* __restrict__ out)
{
    __shared__ float hrow[512];
    __shared__ float lg[1000];
    __shared__ float red[8];
    const int b = blockIdx.x, tid = threadIdx.x;

    hrow[tid]       = hl[(size_t)b * 512 + tid];
    hrow[tid + 256] = hl[(size_t)b * 512 + 256 + tid];
    __syncthreads();

    float lmax = -1e30f;
    for (int c = tid; c < 1000; c += 256) {
        const float4* w4 = (const float4*)(Wout + (size_t)c * 512);
        float a0 = 0.f, a1 = 0.f, a2 = 0.f, a3 = 0.f;
        #pragma unroll 4
        for (int k = 0; k < 128; ++k) {
            float4 w = w4[k];
            a0 += hrow[4 * k + 0] * w.x;
            a1 += hrow[4 * k + 1] * w.y;
            a2 += hrow[4 * k + 2] * w.z;
            a3 += hrow[4 * k + 3] * w.w;
        }
        float acc = bout[c] + (a0 + a1) + (a2 + a3);
        lg[c] = acc;
        lmax = fmaxf(lmax, acc);
    }
    #pragma unroll
    for (int off = 32; off; off >>= 1) lmax = fmaxf(lmax, __shfl_down(lmax, off, 64));
    if ((tid & 63) == 0) red[tid >> 6] = lmax;
    __syncthreads();
    if (tid == 0) red[4] = fmaxf(fmaxf(red[0], red[1]), fmaxf(red[2], red[3]));
    __syncthreads();
    const float M = red[4];

    float lsum = 0.f;
    for (int c = tid; c < 1000; c += 256) lsum += __expf(lg[c] - M);
    #pragma unroll
    for (int off = 32; off; off >>= 1) lsum += __shfl_down(lsum, off, 64);
    __syncthreads();
    if ((tid & 63) == 0) red[tid >> 6] = lsum;
    __syncthreads();
    if (tid == 0) red[5] = M + __logf(red[0] + red[1] + red[2] + red[3]);
    __syncthreads();
    const float lse = red[5];

    for (int c = tid; c < 1000; c += 256)
        out[(size_t)b * 1000 + c] = lg[c] - lse;
}

// ---------------------------------------------------------------------------
extern "C" void kernel_launch(void* const* d_in, const int* in_sizes, int n_in,
                              void* d_out, int out_size, void* d_ws, size_t ws_size,
                              hipStream_t stream)
{
    const float* x    = (const float*)d_in[0];
    const float* Wih0 = (const float*)d_in[1];
    const float* Whh0 = (const float*)d_in[2];
    const float* bih0 = (const float*)d_in[3];
    const float* bhh0 = (const float*)d_in[4];
    const float* Wih1 = (const float*)d_in[5];
    const float* Whh1 = (const float*)d_in[6];
    const float* bih1 = (const float*)d_in[7];
    const float* bhh1 = (const float*)d_in[8];
    const float* Wout = (const float*)d_in[9];
    const float* bout = (const float*)d_in[10];
    float* out = (float*)d_out;

    char* ws = (char*)d_ws;
    unsigned short* bufA = (unsigned short*)ws;                              // 64 MB
    unsigned short* bufB = (unsigned short*)(ws + (size_t)64 * 1024 * 1024);
    // layer-0 W pack at bufB head (dead once rec0 finishes; proj1 overwrites)
    signed char* Wq0 = (signed char*)bufB;                                   // 256 KB
    float*       sc0 = (float*)((char*)bufB + 262144);                       // 2 KB
    // layer-1 W pack at bufA head (written after proj1 consumed bufA)
    signed char* Wq1 = (signed char*)bufA;                                   // 256 KB
    float*       sc1 = (float*)(ws + 262144);                                // 2 KB
    float*     hlast = (float*)(ws + (size_t)1 * 1024 * 1024);               // 256 KB

    const dim3 pgrid(8, 512);

    packi8_kernel<<<512, 64, 0, stream>>>(Whh0, Wq0, sc0);
    proj_kernel<128, 0><<<pgrid, 256, 0, stream>>>((const void*)x, Wih0, bih0, bhh0, bufA);
    rec7_kernel<0><<<8, 256, 0, stream>>>(Wq0, sc0, bufA, bufA, hlast);

    proj_kernel<512, 1><<<pgrid, 256, 0, stream>>>((const void*)bufA, Wih1, bih1, bhh1, bufB);
    packi8_kernel<<<512, 64, 0, stream>>>(Whh1, Wq1, sc1);
    rec7_kernel<1><<<8, 256, 0, stream>>>(Wq1, sc1, bufB, bufB, hlast);

    head_kernel<<<128, 256, 0, stream>>>(hlast, Wout, bout, out);
}